// Round 11
// baseline (189.448 us; speedup 1.0000x reference)
//
#include <hip/hip_runtime.h>
#include <math.h>

// MaskedBalancedBCELoss — hard-negative mining via count-histogram select.
//
// R21: DISCRIMINATING EXPERIMENT, kernels byte-identical to R20 (best: 181.4,
// k1=61.7). Two models explain k1's 62us vs the ~39/24.7 diagnostics:
//  (1) straggler: b=800 -> 32 CUs carry 4 blocks vs 224 carry 3; time ~
//      16 wave-iters/CU. b=1024 = exactly 4 blocks/CU x 3 iters = 12 ->
//      predicts k1 ~46-48us.
//  (2) clock-ramp/BW: 157MB/62us = 2.53 TB/s = 10 B/cy/CU x 256CU x ~1.0GHz
//      (unramped clock; all fast diagnostics ran >=80us into the graph at
//      full clock / 6.35 TB/s) -> predicts k1 unchanged ~62us.
// Change is HOST-ONLY: b=1024, nfull4 = floor(n4/4S)*4S = 12S (3 iters per
// thread, exact), k2_tail (already in R20 binary) covers [12S, n4) =
// 131072 float4s (2 iters/thread, ~5us). Zero codegen risk.
// Decode: k1 ~47 -> balance model, keep & continue. k1 ~62 -> ramp/BW
// roofline under this harness protocol -> declare.

#define NBINS1 4096

#define LN2F 0.69314718055994530942f

__device__ __forceinline__ double bin_mid(unsigned b) {
  return (double)__uint_as_float((b << 19) | 0x40000u);
}

// Branchless per-element processing (loss bit-identical to R10..R20).
__device__ __forceinline__ void proc1(float p, float g, float m, unsigned ln,
                                      unsigned& pc, unsigned& nc,
                                      float& psumf, unsigned* __restrict__ hc) {
  bool gpos = (g != 0.0f);
  bool valid = (m != 0.0f);
  bool ispos = valid && gpos;
  bool isneg = valid && !gpos;
  float x = gpos ? p : 1.0f - p;
  float loss = -fmaxf(__log2f(x) * LN2F, -100.0f);
  pc += ispos ? 1u : 0u;
  nc += isneg ? 1u : 0u;
  psumf += ispos ? loss : 0.0f;
  unsigned b = isneg ? (__float_as_uint(loss) >> 19) : (NBINS1 + ln);
  atomicAdd(&hc[b], 1u);
}

// ---------------- Kernel 1: dg_kb1-shaped hot kernel -----------------------
// Covers [0, nfull4) float4s exactly (host guarantees nfull4 % (4*S) == 0).
// NOTHING else lives in this kernel. Byte-identical to R20's k1.
extern "C" __global__ void __launch_bounds__(256, 4)
k1_hist(const float* __restrict__ pred, const float* __restrict__ gt,
        const float* __restrict__ mask, unsigned* __restrict__ hist1,
        float4* __restrict__ wredux, int nfull4) {
  __shared__ unsigned h[NBINS1 + 64];
  for (int i = threadIdx.x; i < NBINS1 + 64; i += blockDim.x) h[i] = 0u;
  __syncthreads();

  const float4* p4 = (const float4*)pred;
  const float4* g4 = (const float4*)gt;
  const float4* m4 = (const float4*)mask;
  int gtid = blockIdx.x * blockDim.x + threadIdx.x;
  int S = gridDim.x * blockDim.x;
  unsigned ln = threadIdx.x & 63;

  unsigned pc = 0, nc = 0;
  float psumf = 0.0f;
  for (int rep = 0; rep < 1; ++rep) {
    for (int i = gtid; i + 3 * S < nfull4; i += 4 * S) {
      int jb = i + rep;
      float4 pv0 = p4[jb], pv1 = p4[jb + S], pv2 = p4[jb + 2 * S], pv3 = p4[jb + 3 * S];
      float4 gv0 = g4[jb], gv1 = g4[jb + S], gv2 = g4[jb + 2 * S], gv3 = g4[jb + 3 * S];
      float4 mv0 = m4[jb], mv1 = m4[jb + S], mv2 = m4[jb + 2 * S], mv3 = m4[jb + 3 * S];
      float pa[16] = {pv0.x, pv0.y, pv0.z, pv0.w, pv1.x, pv1.y, pv1.z, pv1.w,
                      pv2.x, pv2.y, pv2.z, pv2.w, pv3.x, pv3.y, pv3.z, pv3.w};
      float ga[16] = {gv0.x, gv0.y, gv0.z, gv0.w, gv1.x, gv1.y, gv1.z, gv1.w,
                      gv2.x, gv2.y, gv2.z, gv2.w, gv3.x, gv3.y, gv3.z, gv3.w};
      float ma[16] = {mv0.x, mv0.y, mv0.z, mv0.w, mv1.x, mv1.y, mv1.z, mv1.w,
                      mv2.x, mv2.y, mv2.z, mv2.w, mv3.x, mv3.y, mv3.z, mv3.w};
#pragma unroll
      for (int j = 0; j < 16; j++) {
        bool gpos = (ga[j] != 0.0f);
        bool valid = (ma[j] != 0.0f);
        bool ispos = valid && gpos;
        bool isneg = valid && !gpos;
        float x = gpos ? pa[j] : 1.0f - pa[j];
        float loss = -fmaxf(__log2f(x) * LN2F, -100.0f);
        pc += ispos ? 1u : 0u;
        nc += isneg ? 1u : 0u;
        psumf += ispos ? loss : 0.0f;
        unsigned b = isneg ? (__float_as_uint(loss) >> 19) : (NBINS1 + ln);
        atomicAdd(&h[b], 1u);   // unconditional: no exec-mask branch
      }
    }
  }

  // epilogue, dg_kb1-shaped: f32 shuffle reduce + ONE plain store per wave.
  // counts <= 4096/wave -> exact in f32.
  float fpc = (float)pc, fnc = (float)nc;
  for (int off = 32; off > 0; off >>= 1) {
    fpc += __shfl_down(fpc, off);
    fnc += __shfl_down(fnc, off);
    psumf += __shfl_down(psumf, off);
  }
  if (ln == 0)
    wredux[blockIdx.x * 4 + (threadIdx.x >> 6)] = make_float4(fpc, fnc, psumf, 0.0f);
  __syncthreads();   // all LDS histogram atomics complete
  for (int b = threadIdx.x; b < NBINS1; b += blockDim.x) {
    unsigned c = h[b];
    if (c) atomicAdd(&hist1[b], c);
  }
}

// -------- k2_tail: cold coverage for the leftover range [start4, n4) + n%4.
extern "C" __global__ void __launch_bounds__(256, 4)
k2_tail(const float* __restrict__ pred, const float* __restrict__ gt,
        const float* __restrict__ mask, unsigned* __restrict__ hist1,
        float4* __restrict__ wredux, int start4, int n4, int n, int wbase) {
  __shared__ unsigned h[NBINS1 + 64];
  for (int i = threadIdx.x; i < NBINS1 + 64; i += blockDim.x) h[i] = 0u;
  __syncthreads();

  const float4* p4 = (const float4*)pred;
  const float4* g4 = (const float4*)gt;
  const float4* m4 = (const float4*)mask;
  int gtid = blockIdx.x * blockDim.x + threadIdx.x;
  int S = gridDim.x * blockDim.x;
  unsigned ln = threadIdx.x & 63;

  unsigned pc = 0, nc = 0;
  float psumf = 0.0f;
  for (int i = start4 + gtid; i < n4; i += S) {
    float4 pv = p4[i], gv = g4[i], mv = m4[i];
    proc1(pv.x, gv.x, mv.x, ln, pc, nc, psumf, h);
    proc1(pv.y, gv.y, mv.y, ln, pc, nc, psumf, h);
    proc1(pv.z, gv.z, mv.z, ln, pc, nc, psumf, h);
    proc1(pv.w, gv.w, mv.w, ln, pc, nc, psumf, h);
  }
  for (int t = n4 * 4 + gtid; t < n; t += S) {
    proc1(pred[t], gt[t], mask[t], ln, pc, nc, psumf, h);
  }

  float fpc = (float)pc, fnc = (float)nc;
  for (int off = 32; off > 0; off >>= 1) {
    fpc += __shfl_down(fpc, off);
    fnc += __shfl_down(fnc, off);
    psumf += __shfl_down(psumf, off);
  }
  if (ln == 0)
    wredux[wbase + blockIdx.x * 4 + (threadIdx.x >> 6)] = make_float4(fpc, fnc, psumf, 0.0f);
  __syncthreads();
  for (int b = threadIdx.x; b < NBINS1; b += blockDim.x) {
    unsigned c = h[b];
    if (c) atomicAdd(&hist1[b], c);
  }
}

// ---------- Kernel 5: wredux reduce + select + midpoint neg_sum ------------
extern "C" __global__ void __launch_bounds__(256)
k5_final(const unsigned* __restrict__ hist1, const float4* __restrict__ wredux,
         int nwaves, float* __restrict__ out) {
  const int T = 256, CH = NBINS1 / T;  // 16 bins per thread
  __shared__ unsigned long long sarr[T];
  __shared__ unsigned long long sk;
  __shared__ unsigned sB, skrem;
  __shared__ double sred[4];
  __shared__ double rpc[T], rnc[T], rps[T];
  __shared__ unsigned long long s_pos;
  __shared__ double s_psum;
  int t = threadIdx.x;
  int wv = t >> 6, ln = t & 63;

  // ---- reduce per-wave partials (exact: counts are integers in f32) ----
  double tpc = 0.0, tnc = 0.0, tps = 0.0;
  for (int i = t; i < nwaves; i += T) {
    float4 v = wredux[i];
    tpc += (double)v.x; tnc += (double)v.y; tps += (double)v.z;
  }
  rpc[t] = tpc; rnc[t] = tnc; rps[t] = tps;
  __syncthreads();
  for (int off = T / 2; off > 0; off >>= 1) {
    if (t < off) { rpc[t] += rpc[t + off]; rnc[t] += rnc[t + off]; rps[t] += rps[t + off]; }
    __syncthreads();
  }

  unsigned cnt[CH];
  unsigned long long tot = 0;
  for (int j = 0; j < CH; j++) { cnt[j] = hist1[t * CH + j]; tot += cnt[j]; }
  sarr[t] = tot;
  if (t == 0) {
    sB = 0xFFFFFFFFu; skrem = 0u;
    unsigned long long pos = (unsigned long long)(rpc[0] + 0.5);
    unsigned long long negtot = (unsigned long long)(rnc[0] + 0.5);
    unsigned long long k = 0;
    if (pos > 0) {               // FALLBACK_NEG=0 when pos==0
      k = pos * 3ull;            // floor(pos*3.0), exact in integer
      if (k > negtot) k = negtot;
    }
    sk = k;
    s_pos = pos;
    s_psum = rps[0];
  }
  __syncthreads();
  // inclusive suffix scan: sarr[t] = sum over threads >= t
  for (int off = 1; off < T; off <<= 1) {
    unsigned long long v = (t + off < T) ? sarr[t + off] : 0ull;
    __syncthreads();
    sarr[t] += v;
    __syncthreads();
  }
  unsigned long long k = sk;
  if (k > 0) {
    unsigned long long above = sarr[t] - tot;
    if (above < k && sarr[t] >= k) {
      unsigned long long cum = above;
      for (int j = CH - 1; j >= 0; j--) {
        if (cum + (unsigned long long)cnt[j] >= k) {
          sB = (unsigned)(t * CH + j);
          skrem = (unsigned)(k - cum);
          break;
        }
        cum += cnt[j];
      }
    }
  }
  __syncthreads();
  unsigned B = sB;

  // neg_sum (midpoint model): each thread sums its own bins above B
  double s = 0.0;
  if (B != 0xFFFFFFFFu) {
    for (int j = 0; j < CH; j++) {
      unsigned bi = (unsigned)(t * CH + j);
      if (bi > B && cnt[j]) s += (double)cnt[j] * bin_mid(bi);
    }
  }
  for (int off = 32; off > 0; off >>= 1) s += __shfl_down(s, off);
  if (ln == 0) sred[wv] = s;
  __syncthreads();
  if (t == 0) {
    double neg_sum = sred[0] + sred[1] + sred[2] + sred[3];
    if (skrem > 0 && B != 0xFFFFFFFFu)
      neg_sum += (double)skrem * bin_mid(B);
    double denom = (double)s_pos + (double)k + 1e-6;
    out[0] = (float)((s_psum + neg_sum) / denom);
  }
}

// ---------------------------------------------------------------------------
extern "C" void kernel_launch(void* const* d_in, const int* in_sizes, int n_in,
                              void* d_out, int out_size, void* d_ws, size_t ws_size,
                              hipStream_t stream) {
  const float* pred = (const float*)d_in[0];
  const float* gt   = (const float*)d_in[1];
  const float* mask = (const float*)d_in[2];
  float* out = (float*)d_out;
  int n = in_sizes[0];
  int n4 = n / 4;
  char* ws = (char*)d_ws;

  // R21 grid: b=1024 -> exactly 4 blocks/CU (perfect balance). k1 covers
  // nfull4 = floor(n4 / 4S) * 4S exactly (3 iters/thread for this shape);
  // k2_tail covers [nfull4, n4) + n%4 remainder.
  const int B1 = 1024;
  const int S1 = B1 * 256;
  int nfull4 = (n4 / (4 * S1)) * (4 * S1);
  int need_tail = (nfull4 != n4) || ((n & 3) != 0);
  const int TAILB = 256;
  int nwaves = B1 * 4 + (need_tail ? TAILB * 4 : 0);

  // layout: hist1@256 (16KB) -> zero first 16640B; wredux@64KB (<=144KB)
  const size_t HIST1_OFF = 256;
  const size_t ZERO_BYTES = HIST1_OFF + NBINS1 * sizeof(unsigned);   // 16640
  const size_t WREDUX_OFF = 64 * 1024;

  unsigned* hist1 = (unsigned*)(ws + HIST1_OFF);
  float4* wredux = (float4*)(ws + WREDUX_OFF);

  hipMemsetAsync(d_ws, 0, ZERO_BYTES, stream);
  k1_hist<<<B1, 256, 0, stream>>>(pred, gt, mask, hist1, wredux, nfull4);
  if (need_tail) {
    k2_tail<<<TAILB, 256, 0, stream>>>(pred, gt, mask, hist1, wredux,
                                       nfull4, n4, n, B1 * 4);
  }
  k5_final<<<1, 256, 0, stream>>>(hist1, wredux, nwaves, out);
}